// Round 15
// baseline (67.413 us; speedup 1.0000x reference)
//
#include <hip/hip_runtime.h>
#include <hip/hip_fp16.h>

typedef __bf16 bf16x8 __attribute__((ext_vector_type(8)));
typedef float floatx16 __attribute__((ext_vector_type(16)));
typedef unsigned int uint;
typedef unsigned short ushort;
typedef uint  uintx4  __attribute__((ext_vector_type(4)));
typedef float floatx4 __attribute__((ext_vector_type(4)));

constexpr int Mdim = 256, Ndim = 8192, Kdim = 8192;
constexpr int BN = 64, KSPLIT = 4;
constexpr int KS = Kdim / KSPLIT;    // 2048 k per block
constexpr int NT = KS / 64;          // 32 64k-steps, 1 per phase
constexpr int KB = Kdim / 256;       // 32 superblocks per weight row

union U8 { uint u[4]; bf16x8 v; };

__device__ __forceinline__ uint cvtpk(float lo, float hi) {
  uint r; asm("v_cvt_pk_bf16_f32 %0, %1, %2" : "=v"(r) : "v"(lo), "v"(hi));
  return r;
}
template <typename T>
__device__ __forceinline__ T gld(const void* p) {
  return *(const __attribute__((address_space(1))) T*)p;
}
__device__ __forceinline__ void glds16(const void* g, void* l) {
  __builtin_amdgcn_global_load_lds(
      (const __attribute__((address_space(1))) uint*)g,
      (__attribute__((address_space(3))) uint*)l, 16, 0, 0);
}
// B LDS: 64 rows x 64 ushort; 8 chunks of 16B, XOR-swizzled (R6-verified)
__device__ __forceinline__ int bswz(int row, int ch) {
  return row * 64 + ((ch ^ (row & 7)) << 3);
}
#define WAITVM_(n) asm volatile("s_waitcnt vmcnt(" #n ")" ::: "memory")
#define WAITVM(n) WAITVM_(n)

template<bool PRE, bool PART>
__global__ __launch_bounds__(256, 2)
void q4k_gemm(const float* __restrict__ x, const bf16x8* __restrict__ xbf,
              const int* __restrict__ qw, const float* __restrict__ bias,
              float* __restrict__ out, float* __restrict__ pout)
{
  __shared__ __align__(16) int Qs[6 * 2048];   // qs DMA ring: 6 slots x 8 KB
  __shared__ ushort Bb[2][BN * 64];            // bf16 B: 8 KB x 2

  const int tid = threadIdx.x;
  const int bid = blockIdx.x;
  // bijective XCD swizzle (512 blocks): ks-siblings of one n-tile co-XCD
  const int l  = (bid & 7) * 64 + (bid >> 3);
  const int nb = l >> 2;              // 0..127
  const int ks = l & 3;
  const int n0 = nb * BN;
  const int ks8 = ks * (KS >> 8);

  const int sr = tid >> 2;   // dequant row 0..63
  const int sq = tid & 3;    // 8-int slice within the 32-int qs region

  const int lane = tid & 63;
  const int wave = tid >> 6;
  const int mb0  = wave * 2;          // two 32-row m-frags per wave
  const int brow = lane & 31;
  const int bco  = lane >> 5;

  const int* bp0 = qw + (n0 + sr) * (KB * 144);
  const bf16x8* xA0 = PRE ? (xbf + ((mb0    ) * 512 + ks * 128) * 64 + lane) : nullptr;
  const bf16x8* xA1 = PRE ? (xbf + ((mb0 + 1) * 512 + ks * 128) * 64 + lane) : nullptr;

  uintx4 Mdd[2], M0[2], M1[2], M2[2];  // meta: 2 superblock slots (regs)
  U8 pqL, pqH;
  bf16x8 aE[8], aO[8];                 // A frags, alternating by phase parity
  floatx16 acc00 = {}, acc01 = {}, acc10 = {}, acc11 = {};

  // DMA step s's raw qs (64 rows x 128B) into ring slot (R10-verified):
  // linear LDS dest, source pre-swizzled: LDS[row][p] = global chunk p^(row&7)
  auto stageQ = [&](int s, int slot) {
    const int sb = s >> 2, c64 = s & 3;
    const int schk = ((lane & 7) ^ (lane >> 3)) << 2;
    #pragma unroll
    for (int j = 0; j < 2; ++j) {
      const int r = j * 32 + wave * 8 + (lane >> 3);
      const int* src = qw + (n0 + r) * (KB * 144) + (ks8 + sb) * 144
                       + 16 + c64 * 32 + schk;
      glds16((const void*)src, (void*)&Qs[slot * 2048 + (j * 256 + wave * 64) * 4]);
    }
  };

  auto mload = [&](int sbrel, int ms) {
    const int* bp = bp0 + (ks8 + sbrel) * 144;
    Mdd[ms] = gld<uintx4>(bp);
    M0[ms]  = gld<uintx4>(bp + 4);
    M1[ms]  = gld<uintx4>(bp + 8);
    M2[ms]  = gld<uintx4>(bp + 12);
  };

  auto gloadA = [&](int t, bf16x8 (&A)[8]) {
    if constexpr (PRE) {
      const int f = t * 4 * 64;
      #pragma unroll
      for (int kk = 0; kk < 4; ++kk) {
        A[kk]     = gld<bf16x8>(xA0 + f + kk * 64);
        A[4 + kk] = gld<bf16x8>(xA1 + f + kk * 64);
      }
    } else {
      const int kg = ks * KS + t * 64 + bco * 8;
      #pragma unroll
      for (int kk = 0; kk < 4; ++kk) {
        const float* fA = x + (mb0 * 32 + brow) * Kdim + kg + kk * 16;
        const float* fB = x + ((mb0 + 1) * 32 + brow) * Kdim + kg + kk * 16;
        const floatx4 p0 = gld<floatx4>(fA), p1 = gld<floatx4>(fA + 4);
        const floatx4 q0 = gld<floatx4>(fB), q1 = gld<floatx4>(fB + 4);
        U8 ua, ub;
        ua.u[0] = cvtpk(p0.x, p0.y); ua.u[1] = cvtpk(p0.z, p0.w);
        ua.u[2] = cvtpk(p1.x, p1.y); ua.u[3] = cvtpk(p1.z, p1.w);
        ub.u[0] = cvtpk(q0.x, q0.y); ub.u[1] = cvtpk(q0.z, q0.w);
        ub.u[2] = cvtpk(q1.x, q1.y); ub.u[3] = cvtpk(q1.z, q1.w);
        A[kk] = ua.v; A[4 + kk] = ub.v;
      }
    }
  };

  // dequant step (c=s&3) row sr from ring slot via swizzled ds_read (R10)
  auto dequant = [&](int c, int slot, int ms) {
    const int* qrow = &Qs[slot * 2048 + sr * 32];
    const uintx4 q0 = *(const uintx4*)(qrow + (((2 * sq)     ^ (sr & 7)) << 2));
    const uintx4 q1 = *(const uintx4*)(qrow + (((2 * sq + 1) ^ (sr & 7)) << 2));
    const uintx4 dd = Mdd[ms];
    const float d  = __half2float(__ushort_as_half((ushort)((dd.x & 255u) | ((dd.y & 255u) << 8))));
    const float dm = __half2float(__ushort_as_half((ushort)((dd.z & 255u) | ((dd.w & 255u) << 8))));
    const uintx4 s0 = M0[ms], s1 = M1[ms], s2 = M2[ms];
    uint scA, scB, mnA, mnB;
    if (c == 0)      { scA = s0.x & 63u; scB = s0.y & 63u; mnA = s1.x & 63u; mnB = s1.y & 63u; }
    else if (c == 1) { scA = s0.z & 63u; scB = s0.w & 63u; mnA = s1.z & 63u; mnB = s1.w & 63u; }
    else if (c == 2) {
      scA = (s2.x & 15u) | ((s0.x >> 2) & 48u); scB = (s2.y & 15u) | ((s0.y >> 2) & 48u);
      mnA = (s2.x >> 4)  | ((s1.x >> 2) & 48u); mnB = (s2.y >> 4)  | ((s1.y >> 2) & 48u);
    } else {
      scA = (s2.z & 15u) | ((s0.z >> 2) & 48u); scB = (s2.w & 15u) | ((s0.w >> 2) & 48u);
      mnA = (s2.z >> 4)  | ((s1.z >> 2) & 48u); mnB = (s2.w >> 4)  | ((s1.w >> 2) & 48u);
    }
    const float dlA = d * (float)scA, mlA = dm * (float)mnA;
    const float dlB = d * (float)scB, mlB = dm * (float)mnB;
    float wl[8], wh[8];
    #pragma unroll
    for (int h = 0; h < 2; ++h) {
      const uintx4 qv = h ? q1 : q0;
      wl[h*4+0] = fmaf(dlA, (float)(qv.x & 15u), -mlA);
      wl[h*4+1] = fmaf(dlA, (float)(qv.y & 15u), -mlA);
      wl[h*4+2] = fmaf(dlA, (float)(qv.z & 15u), -mlA);
      wl[h*4+3] = fmaf(dlA, (float)(qv.w & 15u), -mlA);
      wh[h*4+0] = fmaf(dlB, (float)(qv.x >> 4), -mlB);
      wh[h*4+1] = fmaf(dlB, (float)(qv.y >> 4), -mlB);
      wh[h*4+2] = fmaf(dlB, (float)(qv.z >> 4), -mlB);
      wh[h*4+3] = fmaf(dlB, (float)(qv.w >> 4), -mlB);
    }
    #pragma unroll
    for (int p = 0; p < 4; ++p) {
      pqL.u[p] = cvtpk(wl[2*p], wl[2*p+1]);
      pqH.u[p] = cvtpk(wh[2*p], wh[2*p+1]);
    }
  };

  auto bwrite = [&](int bufi) {
    *(bf16x8*)&Bb[bufi][bswz(sr, sq)]     = pqL.v;   // lo: k chunk sq
    *(bf16x8*)&Bb[bufi][bswz(sr, 4 + sq)] = pqH.v;   // hi: k chunk 4+sq
  };

  auto mstep = [&](int bufi, const bf16x8 (&A)[8]) {
    #pragma unroll
    for (int kk = 0; kk < 4; ++kk) {
      const bf16x8 bq0 = *(const bf16x8*)&Bb[bufi][bswz(brow,      kk * 2 + bco)];
      const bf16x8 bq1 = *(const bf16x8*)&Bb[bufi][bswz(brow + 32, kk * 2 + bco)];
      acc00 = __builtin_amdgcn_mfma_f32_32x32x16_bf16(A[kk],     bq0, acc00, 0, 0, 0);
      acc01 = __builtin_amdgcn_mfma_f32_32x32x16_bf16(A[kk],     bq1, acc01, 0, 0, 0);
      acc10 = __builtin_amdgcn_mfma_f32_32x32x16_bf16(A[4 + kk], bq0, acc10, 0, 0, 0);
      acc11 = __builtin_amdgcn_mfma_f32_32x32x16_bf16(A[4 + kk], bq1, acc11, 0, 0, 0);
    }
  };

  // ---------------- prologue ----------------
  // issue order matters for the counted waits below
  stageQ(0, 0); stageQ(1, 1); stageQ(2, 2); stageQ(3, 3);   // 8 DMA
  gloadA(0, aE);                                            // 8
  mload(0, 0); mload(1, 1);                                 // 8
  WAITVM(20);           // certify slots 0,1 (20 issued after stageQ(1))
  __builtin_amdgcn_s_barrier();
  dequant(0, 0, 0);
  bwrite(0);
  asm volatile("s_waitcnt lgkmcnt(0)" ::: "memory");
  __builtin_amdgcn_s_barrier();
  __builtin_amdgcn_sched_barrier(0);

  // ---------------- 32 phases ----------------
  // phase P: A(P+1) issued at TOP (consumed next phase via counted auto-wait
  // ~vmcnt(12) — never drains the queue); qs-DMA(P+4); meta every 4th phase;
  // dequant(P+1) from ring slot (certified 1 barrier ago) -> Bb[(P+1)&1];
  // mstep(P); WAITVM certifies slot(P+2) for next phase's dequant.
  #define PH(P, CA, NA, NVM) {                                               \
    if ((P) + 1 < NT) gloadA((P) + 1, NA);                                   \
    if ((P) + 4 < NT) stageQ((P) + 4, ((P) + 4) % 6);                        \
    if ((P) % 4 == 3 && ((P) + 5) / 4 <= 7)                                  \
      mload(((P) + 5) / 4, (((P) + 5) / 4) & 1);                             \
    __builtin_amdgcn_sched_barrier(0);                                       \
    if ((P) + 1 < NT) {                                                      \
      dequant(((P) + 1) & 3, ((P) + 1) % 6, (((P) + 1) >> 2) & 1);           \
      bwrite(((P) + 1) & 1);                                                 \
    }                                                                        \
    __builtin_amdgcn_s_setprio(1);                                           \
    mstep((P) & 1, CA);                                                      \
    __builtin_amdgcn_s_setprio(0);                                           \
    NVM;                                                                     \
    asm volatile("s_waitcnt lgkmcnt(0)" ::: "memory");                       \
    __builtin_amdgcn_s_barrier();                                            \
    __builtin_amdgcn_sched_barrier(0);                                       \
  }

  PH(0,  aE, aO, WAITVM(20)) PH(1,  aO, aE, WAITVM(20))
  PH(2,  aE, aO, WAITVM(20)) PH(3,  aO, aE, WAITVM(20))
  PH(4,  aE, aO, WAITVM(20)) PH(5,  aO, aE, WAITVM(20))
  PH(6,  aE, aO, WAITVM(20)) PH(7,  aO, aE, WAITVM(20))
  PH(8,  aE, aO, WAITVM(20)) PH(9,  aO, aE, WAITVM(20))
  PH(10, aE, aO, WAITVM(20)) PH(11, aO, aE, WAITVM(20))
  PH(12, aE, aO, WAITVM(20)) PH(13, aO, aE, WAITVM(20))
  PH(14, aE, aO, WAITVM(20)) PH(15, aO, aE, WAITVM(20))
  PH(16, aE, aO, WAITVM(20)) PH(17, aO, aE, WAITVM(20))
  PH(18, aE, aO, WAITVM(20)) PH(19, aO, aE, WAITVM(20))
  PH(20, aE, aO, WAITVM(20)) PH(21, aO, aE, WAITVM(20))
  PH(22, aE, aO, WAITVM(20)) PH(23, aO, aE, WAITVM(20))
  PH(24, aE, aO, WAITVM(20)) PH(25, aO, aE, WAITVM(20))
  PH(26, aE, aO, WAITVM(20)) PH(27, aO, aE, WAITVM(20))
  PH(28, aE, aO, WAITVM(16)) PH(29, aO, aE, WAITVM(12))
  PH(30, aE, aO, (void)0)    PH(31, aO, aE, (void)0)
  #undef PH

  // epilogue: D layout col=lane&31, row=(r&3)+8*(r>>2)+4*(lane>>5)  [m74/m101]
  const int gn0 = n0 + (lane & 31);
  const int gn1 = gn0 + 32;
  const int mrow = wave * 64 + 4 * (lane >> 5);
  if constexpr (PART) {
    float* pp = pout + (size_t)ks * ((size_t)Mdim * Ndim);
    #pragma unroll
    for (int r = 0; r < 16; ++r) {
      const int m = mrow + (r & 3) + 8 * (r >> 2);
      pp[m * Ndim + gn0] = acc00[r];
      pp[m * Ndim + gn1] = acc01[r];
      pp[(m + 32) * Ndim + gn0] = acc10[r];
      pp[(m + 32) * Ndim + gn1] = acc11[r];
    }
  } else {
    const float bv0 = (ks == 0) ? bias[gn0] : 0.0f;
    const float bv1 = (ks == 0) ? bias[gn1] : 0.0f;
    #pragma unroll
    for (int r = 0; r < 16; ++r) {
      const int m = mrow + (r & 3) + 8 * (r >> 2);
      atomicAdd(&out[m * Ndim + gn0], acc00[r] + bv0);
      atomicAdd(&out[m * Ndim + gn1], acc01[r] + bv1);
      atomicAdd(&out[(m + 32) * Ndim + gn0], acc10[r] + bv0);
      atomicAdd(&out[(m + 32) * Ndim + gn1], acc11[r] + bv1);
    }
  }
}

// sum 4 partial buffers + bias -> out (streaming, float4)
__global__ __launch_bounds__(256)
void reduce4(const floatx4* __restrict__ p, const float* __restrict__ bias,
             floatx4* __restrict__ out)
{
  const int gid = blockIdx.x * 256 + threadIdx.x;       // 524288 float4s
  constexpr int STR = (Mdim * Ndim) / 4;
  floatx4 s = gld<floatx4>(p + gid);
  s += gld<floatx4>(p + gid + STR);
  s += gld<floatx4>(p + gid + 2 * STR);
  s += gld<floatx4>(p + gid + 3 * STR);
  s += gld<floatx4>((const floatx4*)bias + (gid & 2047));
  out[gid] = s;
}

// optionally zero d_out (atomic path) and optionally pre-tile x -> bf16
// MFMA-fragment layout: xb[(mb*512+kb)*64+lane], m = mb*32+(lane&31),
// k = kb*16+(lane>>5)*8
template<bool DOCVT, bool ZERO>
__global__ __launch_bounds__(256)
void prep(const float* __restrict__ x, uintx4* __restrict__ xb,
          floatx4* __restrict__ out)
{
  const int gid = blockIdx.x * 256 + threadIdx.x;
  if (ZERO) {
    out[gid * 2]     = floatx4{0.f, 0.f, 0.f, 0.f};
    out[gid * 2 + 1] = floatx4{0.f, 0.f, 0.f, 0.f};
  }
  if (DOCVT) {
    const int lane = gid & 63;
    const int m = ((gid >> 15) * 32) + (lane & 31);
    const int k = (((gid >> 6) & 511) * 16) + (lane >> 5) * 8;
    const floatx4 f0 = gld<floatx4>(x + m * Kdim + k);
    const floatx4 f1 = gld<floatx4>(x + m * Kdim + k + 4);
    uintx4 st;
    st.x = cvtpk(f0.x, f0.y); st.y = cvtpk(f0.z, f0.w);
    st.z = cvtpk(f1.x, f1.y); st.w = cvtpk(f1.z, f1.w);
    xb[gid] = st;
  }
}

extern "C" void kernel_launch(void* const* d_in, const int* in_sizes, int n_in,
                              void* d_out, int out_size, void* d_ws, size_t ws_size,
                              hipStream_t stream) {
  (void)in_sizes; (void)n_in; (void)out_size;
  const float* x    = (const float*)d_in[0];
  const int*   qw   = (const int*)d_in[1];
  const float* bias = (const float*)d_in[2];
  float* out = (float*)d_out;

  const size_t needXB   = (size_t)Mdim * Kdim * 2;                   // 4 MB
  const size_t needPART = needXB + (size_t)KSPLIT * Mdim * Ndim * 4; // +32 MB
  if (ws_size >= needPART) {
    float* part = (float*)((char*)d_ws + needXB);
    prep<true, false><<<1024, 256, 0, stream>>>(x, (uintx4*)d_ws, (floatx4*)out);
    q4k_gemm<true, true><<<512, 256, 0, stream>>>(
        x, (const bf16x8*)d_ws, qw, bias, out, part);
    reduce4<<<(Mdim * Ndim / 4) / 256, 256, 0, stream>>>(
        (const floatx4*)part, bias, (floatx4*)out);
  } else if (ws_size >= needXB) {
    prep<true, true><<<1024, 256, 0, stream>>>(x, (uintx4*)d_ws, (floatx4*)out);
    q4k_gemm<true, false><<<512, 256, 0, stream>>>(
        x, (const bf16x8*)d_ws, qw, bias, out, nullptr);
  } else {
    prep<false, true><<<1024, 256, 0, stream>>>(x, nullptr, (floatx4*)out);
    q4k_gemm<false, false><<<512, 256, 0, stream>>>(
        x, nullptr, qw, bias, out, nullptr);
  }
}